// Round 1
// baseline (502.500 us; speedup 1.0000x reference)
//
#include <hip/hip_runtime.h>
#include <hip/hip_bf16.h>

using bf16x8 = __attribute__((ext_vector_type(8))) short;
using f32x4  = __attribute__((ext_vector_type(4))) float;
typedef unsigned short u16;

__device__ __forceinline__ u16 f2bf(float f) {
  unsigned int u = __float_as_uint(f);
  u += 0x7FFFu + ((u >> 16) & 1u);
  return (u16)(u >> 16);
}

__device__ __forceinline__ f32x4 mfma16(bf16x8 a, bf16x8 b, f32x4 c) {
  return __builtin_amdgcn_mfma_f32_16x16x32_bf16(a, b, c, 0, 0, 0);
}

// ---------------------------------------------------------------------------
// Projection GEMM: Y = (X @ W^T + bias) * scale, stored bf16.
// mat 0: Q (scale=0.125, normal [B*S, D] layout)
// mat 1: K (normal layout)
// mat 2: V (transposed per-head layout: Y[(b*1024 + n)*1024 + s], n = h*64+e)
// ---------------------------------------------------------------------------
__global__ __launch_bounds__(256) void proj_kernel(
    const float* __restrict__ Xq, const float* __restrict__ Xk, const float* __restrict__ Xv,
    const float* __restrict__ Wq, const float* __restrict__ Wk, const float* __restrict__ Wv,
    const float* __restrict__ Bq, const float* __restrict__ Bk, const float* __restrict__ Bv,
    u16* __restrict__ Yq, u16* __restrict__ Yk, u16* __restrict__ Yv)
{
  const int mat = blockIdx.z;
  const float* X  = (mat == 0) ? Xq : (mat == 1) ? Xk : Xv;
  const float* W  = (mat == 0) ? Wq : (mat == 1) ? Wk : Wv;
  const float* Bi = (mat == 0) ? Bq : (mat == 1) ? Bk : Bv;
  u16* Y = (mat == 0) ? Yq : (mat == 1) ? Yk : Yv;
  const float scale = (mat == 0) ? 0.125f : 1.0f;

  // 40-elem row stride = 80 B: 16B-aligned, 2-way-max bank pattern
  __shared__ u16 As[128][40];
  __shared__ u16 Bs[128][40];

  const int tid  = threadIdx.x;
  const int lane = tid & 63;
  const int w    = tid >> 6;
  const int m0 = blockIdx.y * 128;
  const int n0 = blockIdx.x * 128;
  const int wm = (w >> 1) * 64;
  const int wn = (w & 1) * 64;
  const int fr = lane & 15;
  const int fg = lane >> 4;

  const int sr = tid >> 1;          // staging row 0..127
  const int sc = (tid & 1) * 16;    // staging col 0/16
  const float* ap = X + (size_t)(m0 + sr) * 1024 + sc;
  const float* bp = W + (size_t)(n0 + sr) * 1024 + sc;

  f32x4 zero = {0.f, 0.f, 0.f, 0.f};
  f32x4 acc[4][4];
#pragma unroll
  for (int i = 0; i < 4; i++)
#pragma unroll
    for (int j = 0; j < 4; j++) acc[i][j] = zero;

  for (int kk = 0; kk < 1024; kk += 32) {
    float4 a0 = *(const float4*)(ap + kk + 0);
    float4 a1 = *(const float4*)(ap + kk + 4);
    float4 a2 = *(const float4*)(ap + kk + 8);
    float4 a3 = *(const float4*)(ap + kk + 12);
    float4 b0 = *(const float4*)(bp + kk + 0);
    float4 b1 = *(const float4*)(bp + kk + 4);
    float4 b2 = *(const float4*)(bp + kk + 8);
    float4 b3 = *(const float4*)(bp + kk + 12);
    u16 pa[16], pb[16];
    pa[0]=f2bf(a0.x); pa[1]=f2bf(a0.y); pa[2]=f2bf(a0.z); pa[3]=f2bf(a0.w);
    pa[4]=f2bf(a1.x); pa[5]=f2bf(a1.y); pa[6]=f2bf(a1.z); pa[7]=f2bf(a1.w);
    pa[8]=f2bf(a2.x); pa[9]=f2bf(a2.y); pa[10]=f2bf(a2.z); pa[11]=f2bf(a2.w);
    pa[12]=f2bf(a3.x); pa[13]=f2bf(a3.y); pa[14]=f2bf(a3.z); pa[15]=f2bf(a3.w);
    pb[0]=f2bf(b0.x); pb[1]=f2bf(b0.y); pb[2]=f2bf(b0.z); pb[3]=f2bf(b0.w);
    pb[4]=f2bf(b1.x); pb[5]=f2bf(b1.y); pb[6]=f2bf(b1.z); pb[7]=f2bf(b1.w);
    pb[8]=f2bf(b2.x); pb[9]=f2bf(b2.y); pb[10]=f2bf(b2.z); pb[11]=f2bf(b2.w);
    pb[12]=f2bf(b3.x); pb[13]=f2bf(b3.y); pb[14]=f2bf(b3.z); pb[15]=f2bf(b3.w);

    __syncthreads();  // previous iteration's fragment reads complete
    *reinterpret_cast<int4*>(&As[sr][sc + 0]) = *reinterpret_cast<int4*>(&pa[0]);
    *reinterpret_cast<int4*>(&As[sr][sc + 8]) = *reinterpret_cast<int4*>(&pa[8]);
    *reinterpret_cast<int4*>(&Bs[sr][sc + 0]) = *reinterpret_cast<int4*>(&pb[0]);
    *reinterpret_cast<int4*>(&Bs[sr][sc + 8]) = *reinterpret_cast<int4*>(&pb[8]);
    __syncthreads();

    bf16x8 af[4], bff[4];
#pragma unroll
    for (int i = 0; i < 4; i++) {
      af[i]  = *reinterpret_cast<const bf16x8*>(&As[wm + i*16 + fr][fg*8]);
      bff[i] = *reinterpret_cast<const bf16x8*>(&Bs[wn + i*16 + fr][fg*8]);
    }
#pragma unroll
    for (int i = 0; i < 4; i++)
#pragma unroll
      for (int j = 0; j < 4; j++)
        acc[i][j] = mfma16(af[i], bff[j], acc[i][j]);
  }

  // epilogue: C/D layout row=(lane>>4)*4+reg, col=lane&15
#pragma unroll
  for (int j = 0; j < 4; j++) {
    const int n = n0 + wn + j*16 + fr;
    const float bias = Bi[n];
#pragma unroll
    for (int i = 0; i < 4; i++) {
      const int mbase = m0 + wm + i*16 + fg*4;
      if (mat == 2) {
        u16 pk[4];
#pragma unroll
        for (int r = 0; r < 4; r++) pk[r] = f2bf((acc[i][j][r] + bias) * scale);
        const int bidx = mbase >> 10;
        const int s = mbase & 1023;
        *reinterpret_cast<uint2*>(&Y[((size_t)(bidx * 1024 + n)) * 1024 + s]) =
            *reinterpret_cast<uint2*>(pk);
      } else {
#pragma unroll
        for (int r = 0; r < 4; r++) {
          Y[(size_t)(mbase + r) * 1024 + n] = f2bf((acc[i][j][r] + bias) * scale);
        }
      }
    }
  }
}

// ---------------------------------------------------------------------------
// Attention output kernel. grid (qt=16, h=16, b=8), 256 threads (4 waves).
// Wave w handles q rows [qt*64 + w*16, +16).
// Pass 1: Z = sum_k exp(s - 8)  (fixed shift; scores are O(1), safe in fp32)
// Pass 2: t = tanh(exp(s-8)/Z), O += t @ V. Writes attn_output and rcpZ.
// ---------------------------------------------------------------------------
__global__ __launch_bounds__(256) void attn_out_kernel(
    const u16* __restrict__ Qbf, const u16* __restrict__ Kbf, const u16* __restrict__ Vt,
    float* __restrict__ outA, float* __restrict__ rcpZ)
{
  const int qt = blockIdx.x;
  const int h  = blockIdx.y;
  const int b  = blockIdx.z;
  const int tid  = threadIdx.x;
  const int lane = tid & 63;
  const int w    = tid >> 6;
  const int fr = lane & 15;
  const int fg = lane >> 4;

  __shared__ u16 Ks[32][88];     // 176 B stride: aligned, 2-way bank pattern
  __shared__ u16 Vts[64][40];    // [e][k] (V already transposed in ws)
  __shared__ u16 Tl[4][16][40];  // per-wave t relayout buffer

  const int qbase = qt * 64 + w * 16;

  // Q fragments (registers), Q pre-scaled by 1/8 at projection time
  const u16* qp = Qbf + ((size_t)(b * 1024 + qbase + fr)) * 1024 + h * 64 + fg * 8;
  const bf16x8 qf0 = *reinterpret_cast<const bf16x8*>(qp);
  const bf16x8 qf1 = *reinterpret_cast<const bf16x8*>(qp + 32);

  const int krow = tid >> 3;            // 0..31
  const int koff = (tid & 7) * 8;       // 0..56
  const u16* kp = Kbf + ((size_t)(b * 1024 + krow)) * 1024 + h * 64 + koff;

  const int vrow = tid >> 2;            // 0..63 (e)
  const int voff = (tid & 3) * 8;       // 0..24 (k within tile)
  const u16* vp = Vt + ((size_t)((b * 16 + h) * 64 + vrow)) * 1024 + voff;

  f32x4 zero = {0.f, 0.f, 0.f, 0.f};
  float zacc[4] = {0.f, 0.f, 0.f, 0.f};

  // ---------------- pass 1: Z ----------------
  for (int kt = 0; kt < 32; kt++) {
    int4 kv = *reinterpret_cast<const int4*>(kp + (size_t)kt * 32 * 1024);
    __syncthreads();
    *reinterpret_cast<int4*>(&Ks[krow][koff]) = kv;
    __syncthreads();

    f32x4 s0 = zero, s1 = zero;
    bf16x8 k0a = *reinterpret_cast<const bf16x8*>(&Ks[fr][fg*8]);
    bf16x8 k0b = *reinterpret_cast<const bf16x8*>(&Ks[fr][32 + fg*8]);
    bf16x8 k1a = *reinterpret_cast<const bf16x8*>(&Ks[16 + fr][fg*8]);
    bf16x8 k1b = *reinterpret_cast<const bf16x8*>(&Ks[16 + fr][32 + fg*8]);
    s0 = mfma16(qf0, k0a, s0); s0 = mfma16(qf1, k0b, s0);
    s1 = mfma16(qf0, k1a, s1); s1 = mfma16(qf1, k1b, s1);
#pragma unroll
    for (int r = 0; r < 4; r++)
      zacc[r] += __expf(s0[r] - 8.f) + __expf(s1[r] - 8.f);
  }
#pragma unroll
  for (int r = 0; r < 4; r++) {
    float z = zacc[r];
    z += __shfl_xor(z, 1); z += __shfl_xor(z, 2);
    z += __shfl_xor(z, 4); z += __shfl_xor(z, 8);
    zacc[r] = z;
  }
  float rz[4];
#pragma unroll
  for (int r = 0; r < 4; r++) rz[r] = 1.0f / zacc[r];
  if (fr == 0) {
#pragma unroll
    for (int r = 0; r < 4; r++)
      rcpZ[((size_t)(b * 16 + h)) * 1024 + qbase + fg * 4 + r] = rz[r];
  }

  // ---------------- pass 2: O = tanh(p) @ V ----------------
  f32x4 o[4];
#pragma unroll
  for (int e = 0; e < 4; e++) o[e] = zero;

  for (int kt = 0; kt < 32; kt++) {
    int4 kv = *reinterpret_cast<const int4*>(kp + (size_t)kt * 32 * 1024);
    int4 vv = *reinterpret_cast<const int4*>(vp + kt * 32);
    __syncthreads();
    *reinterpret_cast<int4*>(&Ks[krow][koff]) = kv;
    *reinterpret_cast<int4*>(&Vts[vrow][voff]) = vv;
    __syncthreads();

    f32x4 s0 = zero, s1 = zero;
    bf16x8 k0a = *reinterpret_cast<const bf16x8*>(&Ks[fr][fg*8]);
    bf16x8 k0b = *reinterpret_cast<const bf16x8*>(&Ks[fr][32 + fg*8]);
    bf16x8 k1a = *reinterpret_cast<const bf16x8*>(&Ks[16 + fr][fg*8]);
    bf16x8 k1b = *reinterpret_cast<const bf16x8*>(&Ks[16 + fr][32 + fg*8]);
    s0 = mfma16(qf0, k0a, s0); s0 = mfma16(qf1, k0b, s0);
    s1 = mfma16(qf0, k1a, s1); s1 = mfma16(qf1, k1b, s1);

    // t = tanh(p), stored into per-wave LDS tile in D-layout
#pragma unroll
    for (int r = 0; r < 4; r++) {
      float p0 = __expf(s0[r] - 8.f) * rz[r];
      float p1 = __expf(s1[r] - 8.f) * rz[r];
      float u0 = __expf(-2.f * p0);
      float u1 = __expf(-2.f * p1);
      float t0 = __fdividef(1.f - u0, 1.f + u0);
      float t1 = __fdividef(1.f - u1, 1.f + u1);
      Tl[w][fg*4 + r][fr]      = f2bf(t0);
      Tl[w][fg*4 + r][16 + fr] = f2bf(t1);
    }
    // re-read in A-fragment layout (same wave; lgkmcnt ordering by compiler)
    bf16x8 af = *reinterpret_cast<const bf16x8*>(&Tl[w][fr][fg*8]);
#pragma unroll
    for (int e = 0; e < 4; e++) {
      bf16x8 bv = *reinterpret_cast<const bf16x8*>(&Vts[e*16 + fr][fg*8]);
      o[e] = mfma16(af, bv, o[e]);
    }
  }

#pragma unroll
  for (int e = 0; e < 4; e++)
#pragma unroll
    for (int r = 0; r < 4; r++)
      outA[((size_t)(b * 1024 + qbase + fg*4 + r)) * 1024 + h * 64 + e*16 + fr] = o[e][r];
}

// ---------------------------------------------------------------------------
// Weights kernel: outW[b,q,k] = mean_h tanh(exp(s-8)*rcpZ). grid (qt=32, b=8),
// 512 threads (8 waves). Wave w owns output frag (qi=w>>2, ki=w&3) of the
// [32 q x 64 k] tile for ALL heads -> register accumulation, no races.
// ---------------------------------------------------------------------------
__global__ __launch_bounds__(512) void attn_w_kernel(
    const u16* __restrict__ Qbf, const u16* __restrict__ Kbf,
    const float* __restrict__ rcpZ, float* __restrict__ outW)
{
  const int qt = blockIdx.x;
  const int b  = blockIdx.y;
  const int tid  = threadIdx.x;
  const int lane = tid & 63;
  const int w    = tid >> 6;
  const int qi = w >> 2;
  const int ki = w & 3;
  const int fr = lane & 15;
  const int fg = lane >> 4;

  __shared__ u16 Qall[32][1032];   // 2064 B stride: aligned, 2-way pattern
  __shared__ u16 Ks2[64][88];
  __shared__ float statsL[32][16];

  // stage all-head Q rows for this q-tile
  {
    const int qrow = tid >> 4;            // 0..31
    const int qoffb = (tid & 15) * 64;    // 16 threads x 64 elems cover a row
    const u16* qsrc = Qbf + ((size_t)(b * 1024 + qt * 32 + qrow)) * 1024 + qoffb;
#pragma unroll
    for (int i = 0; i < 8; i++)
      *reinterpret_cast<int4*>(&Qall[qrow][qoffb + i*8]) =
          *reinterpret_cast<const int4*>(qsrc + i*8);
    const int r = tid >> 4, hh = tid & 15;
    statsL[r][hh] = rcpZ[((size_t)(b * 16 + hh)) * 1024 + qt * 32 + r];
  }
  __syncthreads();

  const int krow = tid >> 3;          // 0..63
  const int koff = (tid & 7) * 8;     // 0..56

  for (int kt = 0; kt < 16; kt++) {
    f32x4 wsum = {0.f, 0.f, 0.f, 0.f};
    for (int h = 0; h < 16; h++) {
      const u16* ksrc = Kbf + ((size_t)(b * 1024 + kt * 64 + krow)) * 1024 + h * 64 + koff;
      int4 kv = *reinterpret_cast<const int4*>(ksrc);
      __syncthreads();
      *reinterpret_cast<int4*>(&Ks2[krow][koff]) = kv;
      __syncthreads();

      f32x4 s = {0.f, 0.f, 0.f, 0.f};
      bf16x8 a0 = *reinterpret_cast<const bf16x8*>(&Qall[qi*16 + fr][h*64 + fg*8]);
      bf16x8 a1 = *reinterpret_cast<const bf16x8*>(&Qall[qi*16 + fr][h*64 + 32 + fg*8]);
      bf16x8 b0 = *reinterpret_cast<const bf16x8*>(&Ks2[ki*16 + fr][fg*8]);
      bf16x8 b1 = *reinterpret_cast<const bf16x8*>(&Ks2[ki*16 + fr][32 + fg*8]);
      s = mfma16(a0, b0, s);
      s = mfma16(a1, b1, s);
#pragma unroll
      for (int r = 0; r < 4; r++) {
        float rzv = statsL[qi*16 + fg*4 + r][h];
        float p = __expf(s[r] - 8.f) * rzv;
        float u = __expf(-2.f * p);
        wsum[r] += __fdividef(1.f - u, 1.f + u);
      }
    }
#pragma unroll
    for (int r = 0; r < 4; r++) {
      outW[((size_t)(b * 1024 + qt*32 + qi*16 + fg*4 + r)) * 1024 + kt*64 + ki*16 + fr] =
          wsum[r] * 0.0625f;
    }
  }
}

// ---------------------------------------------------------------------------
extern "C" void kernel_launch(void* const* d_in, const int* in_sizes, int n_in,
                              void* d_out, int out_size, void* d_ws, size_t ws_size,
                              hipStream_t stream) {
  const float* query = (const float*)d_in[0];
  const float* key_  = (const float*)d_in[1];
  const float* value = (const float*)d_in[2];
  const float* Wq = (const float*)d_in[3];
  const float* bq = (const float*)d_in[4];
  const float* Wk = (const float*)d_in[5];
  const float* bk = (const float*)d_in[6];
  const float* Wv = (const float*)d_in[7];
  const float* bv = (const float*)d_in[8];

  float* outA = (float*)d_out;            // [8,1024,1024]
  float* outW = outA + 8388608;           // [8,1024,1024]

  u16* Qbf = (u16*)d_ws;                  // bf16, Q pre-scaled by 1/8
  u16* Kbf = Qbf + 8388608;
  u16* Vt  = Kbf + 8388608;               // [B,H,64,S] transposed per head
  float* rcpZ = (float*)(Vt + 8388608);   // [B,H,S]

  proj_kernel<<<dim3(8, 64, 3), 256, 0, stream>>>(
      query, key_, value, Wq, Wk, Wv, bq, bk, bv, Qbf, Kbf, Vt);
  attn_out_kernel<<<dim3(16, 16, 8), 256, 0, stream>>>(Qbf, Kbf, Vt, outA, rcpZ);
  attn_w_kernel<<<dim3(32, 8), 512, 0, stream>>>(Qbf, Kbf, rcpZ, outW);
}

// Round 2
// 501.940 us; speedup vs baseline: 1.0011x; 1.0011x over previous
//
#include <hip/hip_runtime.h>
#include <hip/hip_bf16.h>

using bf16x8 = __attribute__((ext_vector_type(8))) short;
using f32x4  = __attribute__((ext_vector_type(4))) float;
typedef unsigned short u16;

__device__ __forceinline__ u16 f2bf(float f) {
  unsigned int u = __float_as_uint(f);
  u += 0x7FFFu + ((u >> 16) & 1u);
  return (u16)(u >> 16);
}

__device__ __forceinline__ f32x4 mfma16(bf16x8 a, bf16x8 b, f32x4 c) {
  return __builtin_amdgcn_mfma_f32_16x16x32_bf16(a, b, c, 0, 0, 0);
}

// ---------------------------------------------------------------------------
// Projection GEMM: Y = (X @ W^T + bias) * scale, stored bf16.
// mat 0: Q (scale=0.125, normal [B*S, D] layout)
// mat 1: K (normal layout)
// mat 2: V (transposed per-head layout: Y[(b*1024 + n)*1024 + s], n = h*64+e)
// ---------------------------------------------------------------------------
__global__ __launch_bounds__(256) void proj_kernel(
    const float* __restrict__ Xq, const float* __restrict__ Xk, const float* __restrict__ Xv,
    const float* __restrict__ Wq, const float* __restrict__ Wk, const float* __restrict__ Wv,
    const float* __restrict__ Bq, const float* __restrict__ Bk, const float* __restrict__ Bv,
    u16* __restrict__ Yq, u16* __restrict__ Yk, u16* __restrict__ Yv)
{
  const int mat = blockIdx.z;
  const float* X  = (mat == 0) ? Xq : (mat == 1) ? Xk : Xv;
  const float* W  = (mat == 0) ? Wq : (mat == 1) ? Wk : Wv;
  const float* Bi = (mat == 0) ? Bq : (mat == 1) ? Bk : Bv;
  u16* Y = (mat == 0) ? Yq : (mat == 1) ? Yk : Yv;
  const float scale = (mat == 0) ? 0.125f : 1.0f;

  // 40-elem row stride = 80 B: 16B-aligned, 2-way-max bank pattern
  __shared__ u16 As[128][40];
  __shared__ u16 Bs[128][40];

  const int tid  = threadIdx.x;
  const int lane = tid & 63;
  const int w    = tid >> 6;
  const int m0 = blockIdx.y * 128;
  const int n0 = blockIdx.x * 128;
  const int wm = (w >> 1) * 64;
  const int wn = (w & 1) * 64;
  const int fr = lane & 15;
  const int fg = lane >> 4;

  const int sr = tid >> 1;          // staging row 0..127
  const int sc = (tid & 1) * 16;    // staging col 0/16
  const float* ap = X + (size_t)(m0 + sr) * 1024 + sc;
  const float* bp = W + (size_t)(n0 + sr) * 1024 + sc;

  f32x4 zero = {0.f, 0.f, 0.f, 0.f};
  f32x4 acc[4][4];
#pragma unroll
  for (int i = 0; i < 4; i++)
#pragma unroll
    for (int j = 0; j < 4; j++) acc[i][j] = zero;

  for (int kk = 0; kk < 1024; kk += 32) {
    float4 a0 = *(const float4*)(ap + kk + 0);
    float4 a1 = *(const float4*)(ap + kk + 4);
    float4 a2 = *(const float4*)(ap + kk + 8);
    float4 a3 = *(const float4*)(ap + kk + 12);
    float4 b0 = *(const float4*)(bp + kk + 0);
    float4 b1 = *(const float4*)(bp + kk + 4);
    float4 b2 = *(const float4*)(bp + kk + 8);
    float4 b3 = *(const float4*)(bp + kk + 12);
    u16 pa[16], pb[16];
    pa[0]=f2bf(a0.x); pa[1]=f2bf(a0.y); pa[2]=f2bf(a0.z); pa[3]=f2bf(a0.w);
    pa[4]=f2bf(a1.x); pa[5]=f2bf(a1.y); pa[6]=f2bf(a1.z); pa[7]=f2bf(a1.w);
    pa[8]=f2bf(a2.x); pa[9]=f2bf(a2.y); pa[10]=f2bf(a2.z); pa[11]=f2bf(a2.w);
    pa[12]=f2bf(a3.x); pa[13]=f2bf(a3.y); pa[14]=f2bf(a3.z); pa[15]=f2bf(a3.w);
    pb[0]=f2bf(b0.x); pb[1]=f2bf(b0.y); pb[2]=f2bf(b0.z); pb[3]=f2bf(b0.w);
    pb[4]=f2bf(b1.x); pb[5]=f2bf(b1.y); pb[6]=f2bf(b1.z); pb[7]=f2bf(b1.w);
    pb[8]=f2bf(b2.x); pb[9]=f2bf(b2.y); pb[10]=f2bf(b2.z); pb[11]=f2bf(b2.w);
    pb[12]=f2bf(b3.x); pb[13]=f2bf(b3.y); pb[14]=f2bf(b3.z); pb[15]=f2bf(b3.w);

    __syncthreads();  // previous iteration's fragment reads complete
    *reinterpret_cast<int4*>(&As[sr][sc + 0]) = *reinterpret_cast<int4*>(&pa[0]);
    *reinterpret_cast<int4*>(&As[sr][sc + 8]) = *reinterpret_cast<int4*>(&pa[8]);
    *reinterpret_cast<int4*>(&Bs[sr][sc + 0]) = *reinterpret_cast<int4*>(&pb[0]);
    *reinterpret_cast<int4*>(&Bs[sr][sc + 8]) = *reinterpret_cast<int4*>(&pb[8]);
    __syncthreads();

    bf16x8 af[4], bff[4];
#pragma unroll
    for (int i = 0; i < 4; i++) {
      af[i]  = *reinterpret_cast<const bf16x8*>(&As[wm + i*16 + fr][fg*8]);
      bff[i] = *reinterpret_cast<const bf16x8*>(&Bs[wn + i*16 + fr][fg*8]);
    }
#pragma unroll
    for (int i = 0; i < 4; i++)
#pragma unroll
      for (int j = 0; j < 4; j++)
        acc[i][j] = mfma16(af[i], bff[j], acc[i][j]);
  }

  // epilogue: C/D layout row=(lane>>4)*4+reg, col=lane&15
#pragma unroll
  for (int j = 0; j < 4; j++) {
    const int n = n0 + wn + j*16 + fr;
    const float bias = Bi[n];
#pragma unroll
    for (int i = 0; i < 4; i++) {
      const int mbase = m0 + wm + i*16 + fg*4;
      if (mat == 2) {
        u16 pk[4];
#pragma unroll
        for (int r = 0; r < 4; r++) pk[r] = f2bf((acc[i][j][r] + bias) * scale);
        const int bidx = mbase >> 10;
        const int s = mbase & 1023;
        *reinterpret_cast<uint2*>(&Y[((size_t)(bidx * 1024 + n)) * 1024 + s]) =
            *reinterpret_cast<uint2*>(pk);
      } else {
#pragma unroll
        for (int r = 0; r < 4; r++) {
          Y[(size_t)(mbase + r) * 1024 + n] = f2bf((acc[i][j][r] + bias) * scale);
        }
      }
    }
  }
}

// ---------------------------------------------------------------------------
// Attention output kernel. grid (qt=16, h=16, b=8), 256 threads (4 waves).
// Wave w handles q rows [qt*64 + w*16, +16).
// Pass 1: Z = sum_k exp(s - 8)  (fixed shift; scores are O(1), safe in fp32)
// Pass 2: t = tanh(exp(s-8)/Z), O += t @ V. Writes attn_output and rcpZ.
// ---------------------------------------------------------------------------
__global__ __launch_bounds__(256) void attn_out_kernel(
    const u16* __restrict__ Qbf, const u16* __restrict__ Kbf, const u16* __restrict__ Vt,
    float* __restrict__ outA, float* __restrict__ rcpZ)
{
  const int qt = blockIdx.x;
  const int h  = blockIdx.y;
  const int b  = blockIdx.z;
  const int tid  = threadIdx.x;
  const int lane = tid & 63;
  const int w    = tid >> 6;
  const int fr = lane & 15;
  const int fg = lane >> 4;

  __shared__ u16 Ks[32][88];     // 176 B stride: aligned, 2-way bank pattern
  __shared__ u16 Vts[64][40];    // [e][k] (V already transposed in ws)
  __shared__ u16 Tl[4][16][40];  // per-wave t relayout buffer

  const int qbase = qt * 64 + w * 16;

  // Q fragments (registers), Q pre-scaled by 1/8 at projection time
  const u16* qp = Qbf + ((size_t)(b * 1024 + qbase + fr)) * 1024 + h * 64 + fg * 8;
  const bf16x8 qf0 = *reinterpret_cast<const bf16x8*>(qp);
  const bf16x8 qf1 = *reinterpret_cast<const bf16x8*>(qp + 32);

  const int krow = tid >> 3;            // 0..31
  const int koff = (tid & 7) * 8;       // 0..56
  const u16* kp = Kbf + ((size_t)(b * 1024 + krow)) * 1024 + h * 64 + koff;

  const int vrow = tid >> 2;            // 0..63 (e)
  const int voff = (tid & 3) * 8;       // 0..24 (k within tile)
  const u16* vp = Vt + ((size_t)((b * 16 + h) * 64 + vrow)) * 1024 + voff;

  f32x4 zero = {0.f, 0.f, 0.f, 0.f};
  float zacc[4] = {0.f, 0.f, 0.f, 0.f};

  // ---------------- pass 1: Z ----------------
  for (int kt = 0; kt < 32; kt++) {
    int4 kv = *reinterpret_cast<const int4*>(kp + (size_t)kt * 32 * 1024);
    __syncthreads();
    *reinterpret_cast<int4*>(&Ks[krow][koff]) = kv;
    __syncthreads();

    f32x4 s0 = zero, s1 = zero;
    bf16x8 k0a = *reinterpret_cast<const bf16x8*>(&Ks[fr][fg*8]);
    bf16x8 k0b = *reinterpret_cast<const bf16x8*>(&Ks[fr][32 + fg*8]);
    bf16x8 k1a = *reinterpret_cast<const bf16x8*>(&Ks[16 + fr][fg*8]);
    bf16x8 k1b = *reinterpret_cast<const bf16x8*>(&Ks[16 + fr][32 + fg*8]);
    s0 = mfma16(qf0, k0a, s0); s0 = mfma16(qf1, k0b, s0);
    s1 = mfma16(qf0, k1a, s1); s1 = mfma16(qf1, k1b, s1);
#pragma unroll
    for (int r = 0; r < 4; r++)
      zacc[r] += __expf(s0[r] - 8.f) + __expf(s1[r] - 8.f);
  }
#pragma unroll
  for (int r = 0; r < 4; r++) {
    float z = zacc[r];
    z += __shfl_xor(z, 1); z += __shfl_xor(z, 2);
    z += __shfl_xor(z, 4); z += __shfl_xor(z, 8);
    zacc[r] = z;
  }
  float rz[4];
#pragma unroll
  for (int r = 0; r < 4; r++) rz[r] = 1.0f / zacc[r];
  if (fr == 0) {
#pragma unroll
    for (int r = 0; r < 4; r++)
      rcpZ[((size_t)(b * 16 + h)) * 1024 + qbase + fg * 4 + r] = rz[r];
  }

  // ---------------- pass 2: O = tanh(p) @ V ----------------
  f32x4 o[4];
#pragma unroll
  for (int e = 0; e < 4; e++) o[e] = zero;

  for (int kt = 0; kt < 32; kt++) {
    int4 kv = *reinterpret_cast<const int4*>(kp + (size_t)kt * 32 * 1024);
    int4 vv = *reinterpret_cast<const int4*>(vp + kt * 32);
    __syncthreads();
    *reinterpret_cast<int4*>(&Ks[krow][koff]) = kv;
    *reinterpret_cast<int4*>(&Vts[vrow][voff]) = vv;
    __syncthreads();

    f32x4 s0 = zero, s1 = zero;
    bf16x8 k0a = *reinterpret_cast<const bf16x8*>(&Ks[fr][fg*8]);
    bf16x8 k0b = *reinterpret_cast<const bf16x8*>(&Ks[fr][32 + fg*8]);
    bf16x8 k1a = *reinterpret_cast<const bf16x8*>(&Ks[16 + fr][fg*8]);
    bf16x8 k1b = *reinterpret_cast<const bf16x8*>(&Ks[16 + fr][32 + fg*8]);
    s0 = mfma16(qf0, k0a, s0); s0 = mfma16(qf1, k0b, s0);
    s1 = mfma16(qf0, k1a, s1); s1 = mfma16(qf1, k1b, s1);

    // t = tanh(p), stored into per-wave LDS tile in D-layout
#pragma unroll
    for (int r = 0; r < 4; r++) {
      float p0 = __expf(s0[r] - 8.f) * rz[r];
      float p1 = __expf(s1[r] - 8.f) * rz[r];
      float u0 = __expf(-2.f * p0);
      float u1 = __expf(-2.f * p1);
      float t0 = __fdividef(1.f - u0, 1.f + u0);
      float t1 = __fdividef(1.f - u1, 1.f + u1);
      Tl[w][fg*4 + r][fr]      = f2bf(t0);
      Tl[w][fg*4 + r][16 + fr] = f2bf(t1);
    }
    // re-read in A-fragment layout (same wave; lgkmcnt ordering by compiler)
    bf16x8 af = *reinterpret_cast<const bf16x8*>(&Tl[w][fr][fg*8]);
#pragma unroll
    for (int e = 0; e < 4; e++) {
      bf16x8 bv = *reinterpret_cast<const bf16x8*>(&Vts[e*16 + fr][fg*8]);
      o[e] = mfma16(af, bv, o[e]);
    }
  }

#pragma unroll
  for (int e = 0; e < 4; e++)
#pragma unroll
    for (int r = 0; r < 4; r++)
      outA[((size_t)(b * 1024 + qbase + fg*4 + r)) * 1024 + h * 64 + e*16 + fr] = o[e][r];
}

// ---------------------------------------------------------------------------
// Weights kernel: outW[b,q,k] = mean_h tanh(exp(s-8)*rcpZ). grid (qt=32, b=8),
// 512 threads (8 waves). Wave w owns output frag (qi=w>>2, ki=w&3) of the
// [32 q x 64 k] tile for ALL heads -> register accumulation, no races.
// ---------------------------------------------------------------------------
__global__ __launch_bounds__(512) void attn_w_kernel(
    const u16* __restrict__ Qbf, const u16* __restrict__ Kbf,
    const float* __restrict__ rcpZ, float* __restrict__ outW)
{
  const int qt = blockIdx.x;
  const int b  = blockIdx.y;
  const int tid  = threadIdx.x;
  const int lane = tid & 63;
  const int w    = tid >> 6;
  const int qi = w >> 2;
  const int ki = w & 3;
  const int fr = lane & 15;
  const int fg = lane >> 4;

  __shared__ u16 Qall[32][1032];   // 2064 B stride: aligned, 2-way pattern
  __shared__ u16 Ks2[64][88];
  __shared__ float statsL[32][16];

  // stage all-head Q rows for this q-tile
  {
    const int qrow = tid >> 4;            // 0..31
    const int qoffb = (tid & 15) * 64;    // 16 threads x 64 elems cover a row
    const u16* qsrc = Qbf + ((size_t)(b * 1024 + qt * 32 + qrow)) * 1024 + qoffb;
#pragma unroll
    for (int i = 0; i < 8; i++)
      *reinterpret_cast<int4*>(&Qall[qrow][qoffb + i*8]) =
          *reinterpret_cast<const int4*>(qsrc + i*8);
    const int r = tid >> 4, hh = tid & 15;
    statsL[r][hh] = rcpZ[((size_t)(b * 16 + hh)) * 1024 + qt * 32 + r];
  }
  __syncthreads();

  const int krow = tid >> 3;          // 0..63
  const int koff = (tid & 7) * 8;     // 0..56

  for (int kt = 0; kt < 16; kt++) {
    f32x4 wsum = {0.f, 0.f, 0.f, 0.f};
    for (int h = 0; h < 16; h++) {
      const u16* ksrc = Kbf + ((size_t)(b * 1024 + kt * 64 + krow)) * 1024 + h * 64 + koff;
      int4 kv = *reinterpret_cast<const int4*>(ksrc);
      __syncthreads();
      *reinterpret_cast<int4*>(&Ks2[krow][koff]) = kv;
      __syncthreads();

      f32x4 s = {0.f, 0.f, 0.f, 0.f};
      bf16x8 a0 = *reinterpret_cast<const bf16x8*>(&Qall[qi*16 + fr][h*64 + fg*8]);
      bf16x8 a1 = *reinterpret_cast<const bf16x8*>(&Qall[qi*16 + fr][h*64 + 32 + fg*8]);
      bf16x8 b0 = *reinterpret_cast<const bf16x8*>(&Ks2[ki*16 + fr][fg*8]);
      bf16x8 b1 = *reinterpret_cast<const bf16x8*>(&Ks2[ki*16 + fr][32 + fg*8]);
      s = mfma16(a0, b0, s);
      s = mfma16(a1, b1, s);
#pragma unroll
      for (int r = 0; r < 4; r++) {
        float rzv = statsL[qi*16 + fg*4 + r][h];
        float p = __expf(s[r] - 8.f) * rzv;
        float u = __expf(-2.f * p);
        wsum[r] += __fdividef(1.f - u, 1.f + u);
      }
    }
#pragma unroll
    for (int r = 0; r < 4; r++) {
      outW[((size_t)(b * 1024 + qt*32 + qi*16 + fg*4 + r)) * 1024 + kt*64 + ki*16 + fr] =
          wsum[r] * 0.0625f;
    }
  }
}

// ---------------------------------------------------------------------------
extern "C" void kernel_launch(void* const* d_in, const int* in_sizes, int n_in,
                              void* d_out, int out_size, void* d_ws, size_t ws_size,
                              hipStream_t stream) {
  const float* query = (const float*)d_in[0];
  const float* key_  = (const float*)d_in[1];
  const float* value = (const float*)d_in[2];
  const float* Wq = (const float*)d_in[3];
  const float* bq = (const float*)d_in[4];
  const float* Wk = (const float*)d_in[5];
  const float* bk = (const float*)d_in[6];
  const float* Wv = (const float*)d_in[7];
  const float* bv = (const float*)d_in[8];

  float* outA = (float*)d_out;            // [8,1024,1024]
  float* outW = outA + 8388608;           // [8,1024,1024]

  u16* Qbf = (u16*)d_ws;                  // bf16, Q pre-scaled by 1/8
  u16* Kbf = Qbf + 8388608;
  u16* Vt  = Kbf + 8388608;               // [B,H,64,S] transposed per head
  float* rcpZ = (float*)(Vt + 8388608);   // [B,H,S]

  proj_kernel<<<dim3(8, 64, 3), 256, 0, stream>>>(
      query, key_, value, Wq, Wk, Wv, bq, bk, bv, Qbf, Kbf, Vt);
  attn_out_kernel<<<dim3(16, 16, 8), 256, 0, stream>>>(Qbf, Kbf, Vt, outA, rcpZ);
  attn_w_kernel<<<dim3(32, 8), 512, 0, stream>>>(Qbf, Kbf, rcpZ, outW);
}